// Round 1
// baseline (564.505 us; speedup 1.0000x reference)
//
#include <hip/hip_runtime.h>

#define N_ROWS 16384
#define DIM 256
#define MARGINF 0.3f
#define BM 128
#define BN 128
#define BK 64

typedef __bf16 bf16x8 __attribute__((ext_vector_type(8)));
typedef __bf16 bf16x4 __attribute__((ext_vector_type(4)));
typedef float f32x4 __attribute__((ext_vector_type(4)));

// ------------------------------------------------------------------
// Kernel 1: row-wise L2 normalize fp32 -> bf16 (x and y)
// One wave per row: 64 lanes x float4 = 256 elements.
// ------------------------------------------------------------------
__global__ __launch_bounds__(256) void normalize_kernel(
    const float* __restrict__ x, const float* __restrict__ y,
    __bf16* __restrict__ xn, __bf16* __restrict__ yn) {
  const int wid = threadIdx.x >> 6;
  const int lane = threadIdx.x & 63;
  int r = blockIdx.x * 4 + wid;  // 0 .. 32767
  const float* src;
  __bf16* dst;
  int row;
  if (r < N_ROWS) { src = x; dst = xn; row = r; }
  else            { src = y; dst = yn; row = r - N_ROWS; }
  const float4 v = *reinterpret_cast<const float4*>(src + (size_t)row * DIM + lane * 4);
  float ss = v.x * v.x + v.y * v.y + v.z * v.z + v.w * v.w;
  #pragma unroll
  for (int off = 32; off; off >>= 1) ss += __shfl_xor(ss, off);
  const float scale = 1.0f / fmaxf(sqrtf(ss), 1e-8f);
  bf16x4 o;
  o.x = (__bf16)(v.x * scale);
  o.y = (__bf16)(v.y * scale);
  o.z = (__bf16)(v.z * scale);
  o.w = (__bf16)(v.w * scale);
  *reinterpret_cast<bf16x4*>(dst + (size_t)row * DIM + lane * 4) = o;
}

// ------------------------------------------------------------------
// Kernel 2: S-tile GEMM (bf16 MFMA) + exp + row/col partial reduction.
// 128x128 tile, BK=64 double-buffered via global_load_lds width=16.
// LDS layout per slab: [kc(8)][row(128)][8 bf16] -> conflict-free
// ds_read_b128 (lanes 0..15 stride 16B, 2-way aliasing = free) while
// keeping the linear-destination requirement of global_load_lds.
// ------------------------------------------------------------------
__device__ __forceinline__ void stage_tile(const __bf16* __restrict__ src,
                                           int rowBase, int kt,
                                           short* ldsSlab, int tid) {
  const int wid = tid >> 6;
  #pragma unroll
  for (int it = 0; it < 4; ++it) {
    const int chunk = it * 256 + tid;     // 1024 chunks of 16B per slab
    const int kc = chunk >> 7;            // 0..7
    const int row = chunk & 127;          // 0..127
    const __bf16* g = src + (size_t)(rowBase + row) * DIM + kt * BK + kc * 8;
    short* l = ldsSlab + (size_t)(it * 256 + wid * 64) * 8;  // wave-uniform base
    __builtin_amdgcn_global_load_lds(
        (const __attribute__((address_space(1))) unsigned int*)g,
        (__attribute__((address_space(3))) unsigned int*)l, 16, 0, 0);
  }
}

__global__ __launch_bounds__(256, 2) void gemm_exp_kernel(
    const __bf16* __restrict__ xn, const __bf16* __restrict__ yn,
    float* __restrict__ rowsum, float* __restrict__ colsum,
    float* __restrict__ diag) {
  __shared__ short lds[32768];  // 64 KiB: A[2][8192] then B[2][8192]

  const int tid = threadIdx.x;
  const int wid = tid >> 6;
  const int lane = tid & 63;
  const int wm = wid >> 1, wn = wid & 1;   // 2x2 waves, 64x64 each
  const int grp = lane >> 4, li = lane & 15;

  // XCD-aware swizzle: XCD b%8 owns a 16-row-tile band; within it,
  // 8x32 patches (A 0.5MB + B 2MB -> L2-resident), col-group-major.
  const int b = blockIdx.x;
  const int xcd = b & 7;
  const int local = b >> 3;        // 0..2047
  const int p = local >> 8;        // 8 patches
  const int pi = local & 255;
  const int prow = p & 1, pcol = p >> 1;
  const int by = xcd * 16 + prow * 8 + (pi >> 5);
  const int bx = pcol * 32 + (pi & 31);
  const int rowBase = by * BM;
  const int colBase = bx * BN;

  short* ldsA0 = lds;
  short* ldsB0 = lds + 16384;

  f32x4 acc[4][4];
  #pragma unroll
  for (int m = 0; m < 4; ++m)
    #pragma unroll
    for (int n = 0; n < 4; ++n) acc[m][n] = (f32x4)(0.0f);

  stage_tile(xn, rowBase, 0, ldsA0, tid);
  stage_tile(yn, colBase, 0, ldsB0, tid);
  __syncthreads();

  #pragma unroll
  for (int kt = 0; kt < 4; ++kt) {
    if (kt < 3) {
      const int nb = (kt + 1) & 1;
      stage_tile(xn, rowBase, kt + 1, ldsA0 + nb * 8192, tid);
      stage_tile(yn, colBase, kt + 1, ldsB0 + nb * 8192, tid);
    }
    const int buf = kt & 1;
    short* A = ldsA0 + buf * 8192;
    short* B = ldsB0 + buf * 8192;
    #pragma unroll
    for (int ks = 0; ks < 2; ++ks) {
      bf16x8 a[4], bb[4];
      #pragma unroll
      for (int m = 0; m < 4; ++m)
        a[m] = *reinterpret_cast<const bf16x8*>(
            A + (size_t)(((ks * 4 + grp) * 128) + wm * 64 + m * 16 + li) * 8);
      #pragma unroll
      for (int n = 0; n < 4; ++n)
        bb[n] = *reinterpret_cast<const bf16x8*>(
            B + (size_t)(((ks * 4 + grp) * 128) + wn * 64 + n * 16 + li) * 8);
      #pragma unroll
      for (int m = 0; m < 4; ++m)
        #pragma unroll
        for (int n = 0; n < 4; ++n)
          acc[m][n] = __builtin_amdgcn_mfma_f32_16x16x32_bf16(a[m], bb[n], acc[m][n], 0, 0, 0);
    }
    __syncthreads();
  }

  // Epilogue: exp + partial row/col sums + diag capture.
  // C/D layout (m89/m91): col = lane&15, row = (lane>>4)*4 + j.
  float rsum[4][4];
  float csum[4];
  #pragma unroll
  for (int m = 0; m < 4; ++m)
    #pragma unroll
    for (int j = 0; j < 4; ++j) rsum[m][j] = 0.0f;
  #pragma unroll
  for (int n = 0; n < 4; ++n) csum[n] = 0.0f;

  const bool diagBlock = (by == bx) && (wm == wn);
  #pragma unroll
  for (int m = 0; m < 4; ++m) {
    #pragma unroll
    for (int n = 0; n < 4; ++n) {
      #pragma unroll
      for (int j = 0; j < 4; ++j) {
        const float s = acc[m][n][j];
        const float e = __expf(s);
        rsum[m][j] += e;
        csum[n] += e;
        if (diagBlock && (m == n) && (grp * 4 + j == li)) {
          diag[rowBase + wm * 64 + m * 16 + grp * 4 + j] = s;
        }
      }
    }
  }

  // Row sums: reduce across lanes 0..15 (same row within each grp).
  #pragma unroll
  for (int m = 0; m < 4; ++m) {
    #pragma unroll
    for (int j = 0; j < 4; ++j) {
      float v = rsum[m][j];
      v += __shfl_xor(v, 1);
      v += __shfl_xor(v, 2);
      v += __shfl_xor(v, 4);
      v += __shfl_xor(v, 8);
      if (li == 0)
        atomicAdd(&rowsum[rowBase + wm * 64 + m * 16 + grp * 4 + j], v);
    }
  }
  // Col sums: reduce across the 4 grp groups.
  #pragma unroll
  for (int n = 0; n < 4; ++n) {
    float v = csum[n];
    v += __shfl_xor(v, 16);
    v += __shfl_xor(v, 32);
    if (grp == 0)
      atomicAdd(&colsum[colBase + wn * 64 + n * 16 + li], v);
  }
}

// ------------------------------------------------------------------
// Kernel 3: final loss
// ------------------------------------------------------------------
__global__ __launch_bounds__(256) void finalize_kernel(
    const float* __restrict__ rowsum, const float* __restrict__ colsum,
    const float* __restrict__ diag, float* __restrict__ out) {
  __shared__ float red[2][4];
  float s1 = 0.0f, s2 = 0.0f;
  for (int i = threadIdx.x; i < N_ROWS; i += 256) {
    const float d = diag[i];
    const float ed = __expf(d);
    const float m = __expf(d - MARGINF);
    s1 += m / (m + rowsum[i] - ed);
    s2 += m / (m + colsum[i] - ed);
  }
  #pragma unroll
  for (int off = 32; off; off >>= 1) {
    s1 += __shfl_xor(s1, off);
    s2 += __shfl_xor(s2, off);
  }
  const int wid = threadIdx.x >> 6;
  const int lane = threadIdx.x & 63;
  if (lane == 0) { red[0][wid] = s1; red[1][wid] = s2; }
  __syncthreads();
  if (threadIdx.x == 0) {
    float t1 = 0.0f, t2 = 0.0f;
    #pragma unroll
    for (int w = 0; w < 4; ++w) { t1 += red[0][w]; t2 += red[1][w]; }
    out[0] = -(t1 + t2) / (float)N_ROWS;
  }
}

// ------------------------------------------------------------------
extern "C" void kernel_launch(void* const* d_in, const int* in_sizes, int n_in,
                              void* d_out, int out_size, void* d_ws, size_t ws_size,
                              hipStream_t stream) {
  const float* x = (const float*)d_in[0];
  const float* y = (const float*)d_in[1];
  char* ws = (char*)d_ws;
  __bf16* xn = (__bf16*)ws;                               // 8 MiB
  __bf16* yn = (__bf16*)(ws + 8388608);                   // 8 MiB
  float* rowsum = (float*)(ws + 16777216);                // 64 KiB
  float* colsum = (float*)(ws + 16777216 + 65536);        // 64 KiB
  float* diag   = (float*)(ws + 16777216 + 131072);       // 64 KiB

  hipMemsetAsync(rowsum, 0, 2 * 65536, stream);           // rowsum + colsum
  normalize_kernel<<<8192, 256, 0, stream>>>(x, y, xn, yn);
  gemm_exp_kernel<<<16384, 256, 0, stream>>>(xn, yn, rowsum, colsum, diag);
  finalize_kernel<<<1, 256, 0, stream>>>(rowsum, colsum, diag, (float*)d_out);
}

// Round 2
// 195.943 us; speedup vs baseline: 2.8810x; 2.8810x over previous
//
#include <hip/hip_runtime.h>

#define N_ROWS 16384
#define DIM 256
#define MARGINF 0.3f
#define NT 32          // B tiles per column chunk
#define CHUNK_COLS 4096

typedef __bf16 bf16x8 __attribute__((ext_vector_type(8)));
typedef __bf16 bf16x4 __attribute__((ext_vector_type(4)));
typedef float f32x4 __attribute__((ext_vector_type(4)));

// ------------------------------------------------------------------
// Kernel 1: row-wise L2 normalize fp32 -> bf16 (x and y)
// ------------------------------------------------------------------
__global__ __launch_bounds__(256) void normalize_kernel(
    const float* __restrict__ x, const float* __restrict__ y,
    __bf16* __restrict__ xn, __bf16* __restrict__ yn) {
  const int wid = threadIdx.x >> 6;
  const int lane = threadIdx.x & 63;
  int r = blockIdx.x * 4 + wid;  // 0 .. 32767
  const float* src;
  __bf16* dst;
  int row;
  if (r < N_ROWS) { src = x; dst = xn; row = r; }
  else            { src = y; dst = yn; row = r - N_ROWS; }
  const float4 v = *reinterpret_cast<const float4*>(src + (size_t)row * DIM + lane * 4);
  float ss = v.x * v.x + v.y * v.y + v.z * v.z + v.w * v.w;
  #pragma unroll
  for (int off = 32; off; off >>= 1) ss += __shfl_xor(ss, off);
  const float scale = 1.0f / fmaxf(sqrtf(ss), 1e-8f);
  bf16x4 o;
  o.x = (__bf16)(v.x * scale);
  o.y = (__bf16)(v.y * scale);
  o.z = (__bf16)(v.z * scale);
  o.w = (__bf16)(v.w * scale);
  *reinterpret_cast<bf16x4*>(dst + (size_t)row * DIM + lane * 4) = o;
}

// ------------------------------------------------------------------
// Stage one 128-row x 256-K bf16 panel (64 KB) into LDS.
// LDS holds [row(128)][chunk(32)][8 bf16] with the 16B-chunk index
// XOR-swizzled by (row&7) on the GLOBAL side (linear LDS dest, as
// global_load_lds requires). Global reads stay 128B-coalesced since
// the XOR permutes within each 128B group.
// ------------------------------------------------------------------
__device__ __forceinline__ void stage_panel(const __bf16* __restrict__ src, int rowBase,
                                            short* ldsBase, int tid) {
  const int wid = tid >> 6;
  #pragma unroll
  for (int it = 0; it < 8; ++it) {
    const int chunk = it * 512 + tid;   // 4096 x 16B
    const int row = chunk >> 5;         // 0..127
    const int c = chunk & 31;           // chunk-in-row (LDS slot)
    const int kcg = c ^ (row & 7);      // swizzled source chunk
    const __bf16* g = src + (size_t)(rowBase + row) * DIM + kcg * 8;
    short* l = ldsBase + (size_t)(it * 512 + wid * 64) * 8;  // wave-uniform base
    __builtin_amdgcn_global_load_lds(
        (const __attribute__((address_space(1))) unsigned int*)g,
        (__attribute__((address_space(3))) unsigned int*)l, 16, 0, 0);
  }
}

// ------------------------------------------------------------------
// Kernel 2: per block: 128-row A band (registers) x 4096-col chunk.
// 8 waves (2 wm x 4 wn), wave tile 64x32, 16x16x32 bf16 MFMA.
// exp() epilogue feeding register rowsums + LDS colsums.
// ------------------------------------------------------------------
__global__ __launch_bounds__(512, 2) void gemm_exp_kernel(
    const __bf16* __restrict__ xn, const __bf16* __restrict__ yn,
    float* __restrict__ diag, float* __restrict__ rowpart,
    float* __restrict__ colpart, float* __restrict__ rowsum,
    float* __restrict__ colsum, int use_scratch) {
  __shared__ short ldsB[2][32768];   // 128 KiB: B double buffer
  __shared__ float colAcc[4096];     // 16 KiB: per-chunk column sums

  const int tid = threadIdx.x;
  const int wid = tid >> 6, lane = tid & 63;
  const int wm = wid >> 2, wn = wid & 3;
  const int grp = lane >> 4, li = lane & 15;

  const int b = blockIdx.x;
  const int xcd = b & 7, jb = b >> 3;
  const int chunk = xcd & 3;                 // col chunk; shared within XCD -> L2
  const int band = (xcd >> 2) * 64 + jb;     // row band
  const int rowBase = band * 128;
  const int colBase = chunk * CHUNK_COLS;
  const int diagTile = band - chunk * 32;    // in [0,32) iff this block owns diag

  #pragma unroll
  for (int i = 0; i < 8; ++i) colAcc[i * 512 + tid] = 0.0f;

  // ---- A band -> registers (staged through ldsB[0]) ----
  stage_panel(xn, rowBase, &ldsB[0][0], tid);
  __syncthreads();
  bf16x8 a[4][8];
  {
    const short* Ap = &ldsB[0][0];
    #pragma unroll
    for (int ks = 0; ks < 8; ++ks) {
      const int sw = (ks * 4 + grp) ^ (li & 7);
      #pragma unroll
      for (int m = 0; m < 4; ++m) {
        const int row = wm * 64 + m * 16 + li;
        a[m][ks] = *reinterpret_cast<const bf16x8*>(Ap + (size_t)row * 256 + sw * 8);
      }
    }
  }
  __syncthreads();

  float rsum[4][4];
  #pragma unroll
  for (int m = 0; m < 4; ++m)
    #pragma unroll
    for (int j = 0; j < 4; ++j) rsum[m][j] = 0.0f;

  stage_panel(yn, colBase, &ldsB[0][0], tid);
  __syncthreads();

  for (int t = 0; t < NT; ++t) {
    if (t < NT - 1)
      stage_panel(yn, colBase + (t + 1) * 128, &ldsB[(t + 1) & 1][0], tid);

    const short* Bp = &ldsB[t & 1][0];
    f32x4 acc[4][2];
    #pragma unroll
    for (int m = 0; m < 4; ++m) { acc[m][0] = (f32x4)(0.0f); acc[m][1] = (f32x4)(0.0f); }

    #pragma unroll
    for (int ks = 0; ks < 8; ++ks) {
      const int sw = (ks * 4 + grp) ^ (li & 7);
      bf16x8 bb0 = *reinterpret_cast<const bf16x8*>(Bp + (size_t)(wn * 32 + li) * 256 + sw * 8);
      bf16x8 bb1 = *reinterpret_cast<const bf16x8*>(Bp + (size_t)(wn * 32 + 16 + li) * 256 + sw * 8);
      #pragma unroll
      for (int m = 0; m < 4; ++m) {
        acc[m][0] = __builtin_amdgcn_mfma_f32_16x16x32_bf16(a[m][ks], bb0, acc[m][0], 0, 0, 0);
        acc[m][1] = __builtin_amdgcn_mfma_f32_16x16x32_bf16(a[m][ks], bb1, acc[m][1], 0, 0, 0);
      }
    }

    // epilogue: exp + accumulate row/col sums, capture diagonal
    float cs0 = 0.0f, cs1 = 0.0f;
    const bool isDiag = (t == diagTile);
    #pragma unroll
    for (int m = 0; m < 4; ++m) {
      #pragma unroll
      for (int j = 0; j < 4; ++j) {
        const float s0 = acc[m][0][j];
        const float s1 = acc[m][1][j];
        const float e0 = __expf(s0);
        const float e1 = __expf(s1);
        rsum[m][j] += e0 + e1;
        cs0 += e0;
        cs1 += e1;
        if (isDiag) {
          const int r = wm * 64 + m * 16 + grp * 4 + j;
          if (r == wn * 32 + li) diag[rowBase + r] = s0;
          if (r == wn * 32 + 16 + li) diag[rowBase + r] = s1;
        }
      }
    }
    cs0 += __shfl_xor(cs0, 16); cs0 += __shfl_xor(cs0, 32);
    cs1 += __shfl_xor(cs1, 16); cs1 += __shfl_xor(cs1, 32);
    if (grp == 0) {
      const int c0 = t * 128 + wn * 32 + li;
      if (use_scratch) {
        atomicAdd(&colAcc[c0], cs0);
        atomicAdd(&colAcc[c0 + 16], cs1);
      } else {
        atomicAdd(&colsum[colBase + c0], cs0);
        atomicAdd(&colsum[colBase + c0 + 16], cs1);
      }
    }
    __syncthreads();
  }

  // ---- cross-wave reduction of row sums (ldsB free now) ----
  float* rowAcc = reinterpret_cast<float*>(&ldsB[0][0]);  // [4 wn][128 rows]
  #pragma unroll
  for (int m = 0; m < 4; ++m) {
    #pragma unroll
    for (int j = 0; j < 4; ++j) {
      float v = rsum[m][j];
      v += __shfl_xor(v, 1); v += __shfl_xor(v, 2);
      v += __shfl_xor(v, 4); v += __shfl_xor(v, 8);
      if (li == 0) rowAcc[wn * 128 + wm * 64 + m * 16 + grp * 4 + j] = v;
    }
  }
  __syncthreads();
  if (tid < 128) {
    const float v = rowAcc[tid] + rowAcc[128 + tid] + rowAcc[256 + tid] + rowAcc[384 + tid];
    if (use_scratch) rowpart[chunk * N_ROWS + rowBase + tid] = v;
    else atomicAdd(&rowsum[rowBase + tid], v);
  }
  if (use_scratch) {
    #pragma unroll
    for (int i = 0; i < 8; ++i) {
      const int c = i * 512 + tid;
      colpart[(size_t)band * N_ROWS + colBase + c] = colAcc[c];
    }
  }
}

// ------------------------------------------------------------------
// Kernel 3: reduce partials + final loss
// ------------------------------------------------------------------
__global__ __launch_bounds__(256) void finalize_kernel(
    const float* __restrict__ rowpart, const float* __restrict__ colpart,
    const float* __restrict__ rowsum, const float* __restrict__ colsum,
    const float* __restrict__ diag, float* __restrict__ out, int use_scratch) {
  __shared__ float red[4];
  const int i = blockIdx.x * 256 + threadIdx.x;
  float rs, cs;
  if (use_scratch) {
    rs = rowpart[i] + rowpart[N_ROWS + i] + rowpart[2 * N_ROWS + i] + rowpart[3 * N_ROWS + i];
    cs = 0.0f;
    #pragma unroll 8
    for (int bnd = 0; bnd < 128; ++bnd) cs += colpart[(size_t)bnd * N_ROWS + i];
  } else {
    rs = rowsum[i];
    cs = colsum[i];
  }
  const float d = diag[i];
  const float ed = __expf(d);
  const float mm = __expf(d - MARGINF);
  float v = mm / (mm + rs - ed) + mm / (mm + cs - ed);
  #pragma unroll
  for (int off = 32; off; off >>= 1) v += __shfl_xor(v, off);
  if ((threadIdx.x & 63) == 0) red[threadIdx.x >> 6] = v;
  __syncthreads();
  if (threadIdx.x == 0) {
    const float t = red[0] + red[1] + red[2] + red[3];
    atomicAdd(out, -t / (float)N_ROWS);
  }
}

// ------------------------------------------------------------------
extern "C" void kernel_launch(void* const* d_in, const int* in_sizes, int n_in,
                              void* d_out, int out_size, void* d_ws, size_t ws_size,
                              hipStream_t stream) {
  const float* x = (const float*)d_in[0];
  const float* y = (const float*)d_in[1];
  char* ws = (char*)d_ws;
  __bf16* xn = (__bf16*)ws;                                      // 8 MiB
  __bf16* yn = (__bf16*)(ws + (8u << 20));                       // 8 MiB
  float* diag    = (float*)(ws + (16u << 20));                   // 64 KiB
  float* rowsum  = (float*)(ws + (16u << 20) + 65536);           // 64 KiB
  float* colsum  = (float*)(ws + (16u << 20) + 2 * 65536);       // 64 KiB
  float* rowpart = (float*)(ws + (16u << 20) + 3 * 65536);       // 256 KiB [4][N]
  float* colpart = (float*)(ws + (16u << 20) + 3 * 65536 + 262144);  // 8 MiB [128][N]
  const size_t need_scratch = (16u << 20) + 3 * 65536 + 262144 + (8u << 20);
  const int use_scratch = (ws_size >= need_scratch) ? 1 : 0;

  hipMemsetAsync(d_out, 0, sizeof(float), stream);
  if (!use_scratch) hipMemsetAsync(rowsum, 0, 2 * 65536, stream);
  normalize_kernel<<<8192, 256, 0, stream>>>(x, y, xn, yn);
  gemm_exp_kernel<<<512, 512, 0, stream>>>(xn, yn, diag, rowpart, colpart,
                                           rowsum, colsum, use_scratch);
  finalize_kernel<<<64, 256, 0, stream>>>(rowpart, colpart, rowsum, colsum,
                                          diag, (float*)d_out, use_scratch);
}

// Round 3
// 174.718 us; speedup vs baseline: 3.2309x; 1.1215x over previous
//
#include <hip/hip_runtime.h>

#define N_ROWS 16384
#define DIM 256
#define MARGINF 0.3f
#define CHUNK_COLS 2048
#define TILES 32           // 64-col tiles per chunk

typedef __bf16 bf16x8 __attribute__((ext_vector_type(8)));
typedef __bf16 bf16x4 __attribute__((ext_vector_type(4)));
typedef float f32x4 __attribute__((ext_vector_type(4)));

// ------------------------------------------------------------------
// Kernel 1: row-wise L2 normalize fp32 -> bf16 (x and y)
// ------------------------------------------------------------------
__global__ __launch_bounds__(256) void normalize_kernel(
    const float* __restrict__ x, const float* __restrict__ y,
    __bf16* __restrict__ xn, __bf16* __restrict__ yn) {
  const int wid = threadIdx.x >> 6;
  const int lane = threadIdx.x & 63;
  int r = blockIdx.x * 4 + wid;  // 0 .. 32767
  const float* src;
  __bf16* dst;
  int row;
  if (r < N_ROWS) { src = x; dst = xn; row = r; }
  else            { src = y; dst = yn; row = r - N_ROWS; }
  const float4 v = *reinterpret_cast<const float4*>(src + (size_t)row * DIM + lane * 4);
  float ss = v.x * v.x + v.y * v.y + v.z * v.z + v.w * v.w;
  #pragma unroll
  for (int off = 32; off; off >>= 1) ss += __shfl_xor(ss, off);
  const float scale = 1.0f / fmaxf(sqrtf(ss), 1e-8f);
  bf16x4 o;
  o.x = (__bf16)(v.x * scale);
  o.y = (__bf16)(v.y * scale);
  o.z = (__bf16)(v.z * scale);
  o.w = (__bf16)(v.w * scale);
  *reinterpret_cast<bf16x4*>(dst + (size_t)row * DIM + lane * 4) = o;
}

// ------------------------------------------------------------------
// Stage one 64-col x 256-K bf16 panel (32 KB) into LDS.
// LDS [col(64)][slot(32)][8 bf16]; 16B-slot index XOR-swizzled with
// (col&7) on the GLOBAL side (LDS dest stays linear as global_load_lds
// requires; the XOR permutes inside each 512B row -> still coalesced).
// ------------------------------------------------------------------
__device__ __forceinline__ void stage_panel(const __bf16* __restrict__ src,
                                            int colBase, short* ldsBase, int tid) {
  const int wid = tid >> 6;
  #pragma unroll
  for (int it = 0; it < 8; ++it) {
    const int g = it * 256 + tid;       // 2048 x 16B granules
    const int col = g >> 5;             // 0..63
    const int slot = g & 31;            // LDS slot in row
    const int ks = slot ^ (col & 7);    // swizzled source chunk
    const __bf16* gp = src + (size_t)(colBase + col) * DIM + ks * 8;
    short* l = ldsBase + (size_t)(it * 256 + wid * 64) * 8;  // wave-uniform base
    __builtin_amdgcn_global_load_lds(
        (const __attribute__((address_space(1))) unsigned int*)gp,
        (__attribute__((address_space(3))) unsigned int*)l, 16, 0, 0);
  }
}

// ------------------------------------------------------------------
// Kernel 2: block = 128-row band x 2048-col chunk. 4 waves (2wm x 2wn),
// wave tile 64x32. A band in registers (a[4][8], full K=256).
// B streamed in 64-col tiles, double-buffered. Epilogue: exp -> register
// rowsums + atomic-free LDS colsums.
// ------------------------------------------------------------------
__global__ __launch_bounds__(256, 2) void gemm_exp_kernel(
    const __bf16* __restrict__ xn, const __bf16* __restrict__ yn,
    float* __restrict__ diag, float* __restrict__ rowpart,
    float* __restrict__ colpart, float* __restrict__ rowsumG,
    float* __restrict__ colsumG, int use_scratch) {
  __shared__ short ldsB[2][16384];     // 2 x 32 KB B tiles
  __shared__ float colAcc2[2][2048];   // 16 KB, [wm][col], atomic-free

  const int tid = threadIdx.x;
  const int lane = tid & 63;
  const int wid = tid >> 6;
  const int wm = wid >> 1, wn = wid & 1;
  const int grp = lane >> 4, li = lane & 15;

  const int bid = blockIdx.x;
  const int chunk = bid & 7;           // = XCD (round-robin dispatch)
  const int band = bid >> 3;           // 0..127
  const int rowBase = band * 128;
  const int colBase = chunk * CHUNK_COLS;

  // ---- A band -> registers, direct global->reg (L2/L3 resident) ----
  bf16x8 a[4][8];
  #pragma unroll
  for (int m = 0; m < 4; ++m)
    #pragma unroll
    for (int ks = 0; ks < 8; ++ks) {
      const int row = rowBase + wm * 64 + m * 16 + li;
      a[m][ks] = *reinterpret_cast<const bf16x8*>(
          xn + (size_t)row * DIM + (ks * 4 + grp) * 8);
    }

  // init colAcc2 (4096 floats / 256 threads = 16 each)
  {
    float* p = &colAcc2[0][0];
    #pragma unroll
    for (int i = 0; i < 16; ++i) p[i * 256 + tid] = 0.0f;
  }

  stage_panel(yn, colBase, &ldsB[0][0], tid);
  __syncthreads();

  float rsum[4][4];
  #pragma unroll
  for (int m = 0; m < 4; ++m)
    #pragma unroll
    for (int j = 0; j < 4; ++j) rsum[m][j] = 0.0f;

  const int bandDelta = band - chunk * 16;  // diag stripe if in [0,16)

  for (int t = 0; t < TILES; ++t) {
    if (t + 1 < TILES)
      stage_panel(yn, colBase + (t + 1) * 64, &ldsB[(t + 1) & 1][0], tid);

    const short* Bp = &ldsB[t & 1][0];
    f32x4 acc[4][2];
    #pragma unroll
    for (int m = 0; m < 4; ++m) { acc[m][0] = (f32x4)(0.0f); acc[m][1] = (f32x4)(0.0f); }

    #pragma unroll
    for (int ks = 0; ks < 8; ++ks) {
      const int sw = ((ks * 4 + grp) ^ (li & 7)) * 8;
      bf16x8 bb0 = *reinterpret_cast<const bf16x8*>(Bp + (size_t)(wn * 32 + li) * 256 + sw);
      bf16x8 bb1 = *reinterpret_cast<const bf16x8*>(Bp + (size_t)(wn * 32 + 16 + li) * 256 + sw);
      #pragma unroll
      for (int m = 0; m < 4; ++m) {
        acc[m][0] = __builtin_amdgcn_mfma_f32_16x16x32_bf16(a[m][ks], bb0, acc[m][0], 0, 0, 0);
        acc[m][1] = __builtin_amdgcn_mfma_f32_16x16x32_bf16(a[m][ks], bb1, acc[m][1], 0, 0, 0);
      }
    }

    // epilogue: exp + row/col partial sums + diag capture
    float cs0 = 0.0f, cs1 = 0.0f;
    const bool maybeDiag = (bandDelta == (t >> 1));
    #pragma unroll
    for (int m = 0; m < 4; ++m) {
      #pragma unroll
      for (int j = 0; j < 4; ++j) {
        const float s0 = acc[m][0][j];
        const float s1 = acc[m][1][j];
        const float e0 = __expf(s0);
        const float e1 = __expf(s1);
        rsum[m][j] += e0 + e1;
        cs0 += e0;
        cs1 += e1;
        if (maybeDiag) {
          const int rg = rowBase + wm * 64 + m * 16 + grp * 4 + j;
          const int cgBase = colBase + t * 64 + wn * 32 + li;
          if (rg == cgBase) diag[rg] = s0;
          if (rg == cgBase + 16) diag[rg] = s1;
        }
      }
    }
    cs0 += __shfl_xor(cs0, 16); cs0 += __shfl_xor(cs0, 32);
    cs1 += __shfl_xor(cs1, 16); cs1 += __shfl_xor(cs1, 32);
    if (grp == 0) {  // plain stores: unique (wm, col) per t
      colAcc2[wm][t * 64 + wn * 32 + li] = cs0;
      colAcc2[wm][t * 64 + wn * 32 + 16 + li] = cs1;
    }
    __syncthreads();
  }

  // ---- flush column partials (deterministic) ----
  #pragma unroll
  for (int i = 0; i < 8; ++i) {
    const int c = i * 256 + tid;
    const float v = colAcc2[0][c] + colAcc2[1][c];
    if (use_scratch) colpart[(size_t)band * N_ROWS + colBase + c] = v;
    else atomicAdd(&colsumG[colBase + c], v);
  }

  // ---- cross-wave row-sum reduction (reuse ldsB) ----
  float* rowTmp = reinterpret_cast<float*>(&ldsB[0][0]);  // [2 wn][128]
  #pragma unroll
  for (int m = 0; m < 4; ++m) {
    #pragma unroll
    for (int j = 0; j < 4; ++j) {
      float v = rsum[m][j];
      v += __shfl_xor(v, 1); v += __shfl_xor(v, 2);
      v += __shfl_xor(v, 4); v += __shfl_xor(v, 8);
      if (li == 0) rowTmp[wn * 128 + wm * 64 + m * 16 + grp * 4 + j] = v;
    }
  }
  __syncthreads();
  if (tid < 128) {
    const float v = rowTmp[tid] + rowTmp[128 + tid];
    if (use_scratch) rowpart[(size_t)chunk * N_ROWS + rowBase + tid] = v;
    else atomicAdd(&rowsumG[rowBase + tid], v);
  }
}

// ------------------------------------------------------------------
// Kernel 3: reduce partials + final loss
// ------------------------------------------------------------------
__global__ __launch_bounds__(256) void finalize_kernel(
    const float* __restrict__ rowpart, const float* __restrict__ colpart,
    const float* __restrict__ rowsumG, const float* __restrict__ colsumG,
    const float* __restrict__ diag, float* __restrict__ out, int use_scratch) {
  __shared__ float red[4];
  const int i = blockIdx.x * 256 + threadIdx.x;
  float rs, cs;
  if (use_scratch) {
    rs = 0.0f;
    #pragma unroll
    for (int c = 0; c < 8; ++c) rs += rowpart[(size_t)c * N_ROWS + i];
    cs = 0.0f;
    #pragma unroll 8
    for (int b = 0; b < 128; ++b) cs += colpart[(size_t)b * N_ROWS + i];
  } else {
    rs = rowsumG[i];
    cs = colsumG[i];
  }
  const float d = diag[i];
  const float ed = __expf(d);
  const float mm = __expf(d - MARGINF);
  float v = mm / (mm + rs - ed) + mm / (mm + cs - ed);
  #pragma unroll
  for (int off = 32; off; off >>= 1) v += __shfl_xor(v, off);
  if ((threadIdx.x & 63) == 0) red[threadIdx.x >> 6] = v;
  __syncthreads();
  if (threadIdx.x == 0) {
    const float t = red[0] + red[1] + red[2] + red[3];
    atomicAdd(out, -t / (float)N_ROWS);
  }
}

// ------------------------------------------------------------------
extern "C" void kernel_launch(void* const* d_in, const int* in_sizes, int n_in,
                              void* d_out, int out_size, void* d_ws, size_t ws_size,
                              hipStream_t stream) {
  const float* x = (const float*)d_in[0];
  const float* y = (const float*)d_in[1];
  char* ws = (char*)d_ws;
  __bf16* xn = (__bf16*)ws;                                   // 8 MiB
  __bf16* yn = (__bf16*)(ws + (8u << 20));                    // 8 MiB
  float* diag    = (float*)(ws + (16u << 20));                // 64 KiB
  float* rowpart = (float*)(ws + (16u << 20) + 65536);        // 512 KiB [8][N]
  float* colpart = (float*)(ws + (16u << 20) + 65536 + 524288); // 8 MiB [128][N]
  // atomic fallback buffers live inside the rowpart region footprint
  float* rowsumG = rowpart;
  float* colsumG = rowpart + N_ROWS;
  const size_t need_scratch = (16u << 20) + 65536 + 524288 + (8u << 20);
  const int use_scratch = (ws_size >= need_scratch) ? 1 : 0;

  hipMemsetAsync(d_out, 0, sizeof(float), stream);
  if (!use_scratch) hipMemsetAsync(rowsumG, 0, 2 * N_ROWS * sizeof(float), stream);
  normalize_kernel<<<8192, 256, 0, stream>>>(x, y, xn, yn);
  gemm_exp_kernel<<<1024, 256, 0, stream>>>(xn, yn, diag, rowpart, colpart,
                                            rowsumG, colsumG, use_scratch);
  finalize_kernel<<<64, 256, 0, stream>>>(rowpart, colpart, rowsumG, colsumG,
                                          diag, (float*)d_out, use_scratch);
}